// Round 13
// baseline (210.494 us; speedup 1.0000x reference)
//
#include <hip/hip_runtime.h>
#include <hip/hip_bf16.h>
#include <stdint.h>

typedef unsigned short u16;
typedef __bf16 v8bf __attribute__((ext_vector_type(8)));
typedef float  v4f  __attribute__((ext_vector_type(4)));

#define N_ROWS 8192
#define C_REAL 10000
#define C_PAD  10240   /* 40 * 256 */
#define D_DIM  512
#define BM 128
#define BN 256
#define BK 64
#define KTILES (D_DIM / BK)   /* 8 */

/* LDS map (bytes): 3 ring slots of 48KB (A 16KB = 128 rows x 128B swizzled,
   B 32KB = 256 rows x 128B swizzled @+16384), slots @0/49152/98304;
   tables: f2s @147456 (512B), labs @147968 (512B), c2s @148480 (1KB).
   Total 149504 => 1 block/CU (8 waves). Ring staged 2 tiles ahead =>
   counted vmcnt(12) instead of a drain (T4/m218: the drain was the cost). */
#define SLOT0   0
#define SLOT1   49152
#define SLOT2   98304
#define SM_BOFF 16384
#define SM_F2   147456
#define SM_LAB  147968
#define SM_C2   148480
#define SM_TOTAL 149504
static_assert(SM_TOTAL <= 160 * 1024, "LDS budget");

#define NPART 32   /* finalize stage-1 blocks */

#define BARRIER() do { asm volatile("" ::: "memory"); \
                       __builtin_amdgcn_s_barrier();  \
                       asm volatile("" ::: "memory"); } while (0)
#define MFMA(d, a, b) d = __builtin_amdgcn_mfma_f32_16x16x32_bf16(a, b, d, 0, 0, 0)
#define GLL(gp, lp) __builtin_amdgcn_global_load_lds( \
    (const __attribute__((address_space(1))) void*)(gp), \
    (__attribute__((address_space(3))) void*)(lp), 16, 0, 0)

__device__ __forceinline__ unsigned pack2bf(float a, float b) {
    unsigned short ua = __builtin_bit_cast(unsigned short, (__bf16)a);
    unsigned short ub = __builtin_bit_cast(unsigned short, (__bf16)b);
    return (unsigned)ua | ((unsigned)ub << 16);
}

// L2-normalize one row (one wave): bf16 row out + f32 sum-of-squares of the
// normalized row. Padding rows: bf16 zeros, o2 = 1e30 (exp(-5e30) = 0).
__device__ __forceinline__ void norm_row(
    const float* __restrict__ x, u16* __restrict__ ob, float* __restrict__ o2,
    int row, int nreal, int lane)
{
    uint2* orow = (uint2*)(ob + (size_t)row * D_DIM);
    if (row >= nreal) {
        uint2 z; z.x = 0u; z.y = 0u;
        orow[lane] = z; orow[64 + lane] = z;
        if (lane == 0) o2[row] = 1e30f;
        return;
    }
    const float4* xr = (const float4*)(x + (size_t)row * D_DIM);
    float4 v0 = xr[lane];
    float4 v1 = xr[64 + lane];
    float s = v0.x*v0.x + v0.y*v0.y + v0.z*v0.z + v0.w*v0.w
            + v1.x*v1.x + v1.y*v1.y + v1.z*v1.z + v1.w*v1.w;
    #pragma unroll
    for (int m = 1; m < 64; m <<= 1) s += __shfl_xor(s, m, 64);
    float inv = 1.0f / fmaxf(sqrtf(s), 1e-12f);
    if (lane == 0) o2[row] = s * inv * inv;
    uint2 p0, p1;
    p0.x = pack2bf(v0.x * inv, v0.y * inv);
    p0.y = pack2bf(v0.z * inv, v0.w * inv);
    p1.x = pack2bf(v1.x * inv, v1.y * inv);
    p1.y = pack2bf(v1.z * inv, v1.w * inv);
    orow[lane]      = p0;
    orow[64 + lane] = p1;
}

// Exact (f32) positive-class distance for one row (one wave).
__device__ __forceinline__ void pos_row(
    const float* __restrict__ feat, const float* __restrict__ cent,
    const int* __restrict__ labels, float* __restrict__ pose,
    int row, int lane)
{
    int lab = labels[row];
    const float4* fr = (const float4*)(feat + (size_t)row * D_DIM);
    const float4* cr = (const float4*)(cent + (size_t)lab * D_DIM);
    float sf = 0.f, sc = 0.f, sd = 0.f;
    #pragma unroll
    for (int i = 0; i < 2; ++i) {
        float4 a = fr[i * 64 + lane];
        float4 b = cr[i * 64 + lane];
        sf += a.x*a.x + a.y*a.y + a.z*a.z + a.w*a.w;
        sc += b.x*b.x + b.y*b.y + b.z*b.z + b.w*b.w;
        sd += a.x*b.x + a.y*b.y + a.z*b.z + a.w*b.w;
    }
    #pragma unroll
    for (int m = 1; m < 64; m <<= 1) {
        sf += __shfl_xor(sf, m, 64);
        sc += __shfl_xor(sc, m, 64);
        sd += __shfl_xor(sd, m, 64);
    }
    if (lane == 0) {
        float invf = 1.f / fmaxf(sqrtf(sf), 1e-12f);
        float invc = 1.f / fmaxf(sqrtf(sc), 1e-12f);
        pose[row] = -5.0f * (sf * invf * invf + sc * invc * invc
                             - 2.0f * sd * invf * invc);
    }
}

// Fused prep: one launch covers norm(features), norm(centers+pad), pos_exact.
__global__ __launch_bounds__(256) void prep_kernel(
    const float* __restrict__ features, const float* __restrict__ centers,
    const int* __restrict__ labels,
    u16* __restrict__ fb, u16* __restrict__ cb,
    float* __restrict__ f2, float* __restrict__ c2, float* __restrict__ pose)
{
    int b = blockIdx.x;
    int sub = threadIdx.x >> 6;
    int lane = threadIdx.x & 63;
    if (b < 2048) {
        norm_row(features, fb, f2, b * 4 + sub, N_ROWS, lane);
    } else if (b < 4608) {
        norm_row(centers, cb, c2, (b - 2048) * 4 + sub, C_REAL, lane);
    } else {
        pos_row(features, centers, labels, pose, (b - 4608) * 4 + sub, lane);
    }
}

// 128x256x(BK=64) 8-wave MFMA GEMM, 3-slot LDS ring staged 2 tiles ahead.
// Steady-state per tile: {stage(k+2): 6 GLL -> vmcnt(12) (tile k landed,
// 12 newer loads stay in flight) -> barrier -> 16 ds_read_b128 + 32 MFMA
// -> lgkmcnt(0) -> barrier}. The L2 latency of a tile's staging batch is
// hidden under TWO full tiles of compute - no drain until the tail
// (T4/m218: counted-vs-drain0 was the +38-73% lever). Slot k%3 is only
// overwritten by the stage issued in iteration k+1, after iteration k's
// lgkmcnt(0)+barrier => race-free. XOR-8 swizzle (0 conflicts, verified
// r6-r12). Grid (40,64): 40%8==0 => XCD = x%8 => per-XCD B-slice 1.3MB
// L2-resident. Fused exp epilogue; rowsum split per-XCD.
__global__ __launch_bounds__(512, 2) void gemm_kernel(
    const u16* __restrict__ A, const u16* __restrict__ B,
    const float* __restrict__ f2, const float* __restrict__ c2,
    const int* __restrict__ labels,
    float* __restrict__ rowsum, float* __restrict__ posdis)
{
    extern __shared__ char sm[];
    const int rowBase = blockIdx.y * BM;
    const int colBase = blockIdx.x * BN;
    const int tid  = threadIdx.x;
    const int lane = tid & 63;
    const int w    = tid >> 6;      // 0..7
    const int wr   = w >> 2;        // 0..1 : 64-row group
    const int wc   = w & 3;         // 0..3 : 64-col group
    const int l15  = lane & 15;
    const int h4   = lane >> 4;

    // ---- staging geometry: chunk c = tid + i*512, r = (tid>>3) + i*64,
    // pc = tid&7, lc = pc ^ (r&7); (r&7) invariant under +i*64.
    const int r0  = tid >> 3;                       // 0..63
    const int lc0 = (tid & 7) ^ (r0 & 7);
    const size_t gOff = (size_t)r0 * D_DIM + lc0 * 8;   // elements
    const u16* aP = A + (size_t)rowBase * D_DIM + gOff; // +32768 elems per i
    const u16* bP = B + (size_t)colBase * D_DIM + gOff;
    const int d0 = tid * 16;                            // LDS bytes, +8192 per i

    // Stage tile kt (KOFS = kt*64 elems) into slot SL: A 2 chunks, B 4 chunks.
    #define STAGE6(SL, KOFS) do { \
        GLL(aP + (KOFS),         sm + (SL) + d0);                      \
        GLL(aP + (KOFS) + 32768, sm + (SL) + 8192 + d0);               \
        GLL(bP + (KOFS),         sm + (SL) + SM_BOFF + d0);            \
        GLL(bP + (KOFS) + 32768, sm + (SL) + SM_BOFF + 8192 + d0);     \
        GLL(bP + (KOFS) + 65536, sm + (SL) + SM_BOFF + 16384 + d0);    \
        GLL(bP + (KOFS) + 98304, sm + (SL) + SM_BOFF + 24576 + d0);    \
    } while (0)

    // ---- fragment read bases; fragment row = g*64 + m*16 + l15 has
    // row&7 == l15&7 => swizzled byte col = ((ks*4+h4) ^ (l15&7)) * 16.
    const int s0 = ((h4)     ^ (l15 & 7)) << 4;
    const int s1 = ((4 + h4) ^ (l15 & 7)) << 4;
    const int aB0 = wr * 8192 + l15 * 128 + s0;
    const int aB1 = wr * 8192 + l15 * 128 + s1;
    const int bB0 = SM_BOFF + wc * 8192 + l15 * 128 + s0;
    const int bB1 = SM_BOFF + wc * 8192 + l15 * 128 + s1;

    // ---- prologue: tables + stage tiles 0,1 ----
    if (tid < 128) {
        ((float*)(sm + SM_F2))[tid] = f2[rowBase + tid];
        ((int*)(sm + SM_LAB))[tid]  = labels[rowBase + tid];
    } else if (tid < 384) {
        ((float*)(sm + SM_C2))[tid - 128] = c2[colBase + (tid - 128)];
    }
    STAGE6(SLOT0, 0);
    STAGE6(SLOT1, 64);
    __syncthreads();   // drains everything incl. table writes + tile0/1

    v4f acc[4][4];
    #pragma unroll
    for (int m = 0; m < 4; ++m)
        #pragma unroll
        for (int n = 0; n < 4; ++n) acc[m][n] = (v4f){0.f, 0.f, 0.f, 0.f};

    #define COMPUTE(SL) do { \
        v8bf a[4], b[4]; \
        _Pragma("unroll") \
        for (int m = 0; m < 4; ++m) a[m] = *(const v8bf*)(sm + (SL) + aB0 + m * 2048); \
        _Pragma("unroll") \
        for (int n = 0; n < 4; ++n) b[n] = *(const v8bf*)(sm + (SL) + bB0 + n * 2048); \
        __builtin_amdgcn_s_setprio(1); \
        _Pragma("unroll") \
        for (int m = 0; m < 4; ++m) \
            _Pragma("unroll") \
            for (int n = 0; n < 4; ++n) MFMA(acc[m][n], a[m], b[n]); \
        __builtin_amdgcn_s_setprio(0); \
        _Pragma("unroll") \
        for (int m = 0; m < 4; ++m) a[m] = *(const v8bf*)(sm + (SL) + aB1 + m * 2048); \
        _Pragma("unroll") \
        for (int n = 0; n < 4; ++n) b[n] = *(const v8bf*)(sm + (SL) + bB1 + n * 2048); \
        __builtin_amdgcn_s_setprio(1); \
        _Pragma("unroll") \
        for (int m = 0; m < 4; ++m) \
            _Pragma("unroll") \
            for (int n = 0; n < 4; ++n) MFMA(acc[m][n], a[m], b[n]); \
        __builtin_amdgcn_s_setprio(0); \
    } while (0)

    // iter k: stage tile k+2 (if any), counted wait for tile k, compute,
    // then release slot for next iteration's stage.
    #define ITER(SLS, KOFS2, VM, SLC) do { \
        if ((KOFS2) >= 0) STAGE6(SLS, KOFS2); \
        asm volatile("s_waitcnt vmcnt(" #VM ")" ::: "memory"); \
        BARRIER(); \
        COMPUTE(SLC); \
        asm volatile("s_waitcnt lgkmcnt(0)" ::: "memory"); \
        BARRIER(); \
    } while (0)

    ITER(SLOT2, 128, 12, SLOT0);   // k=0: stage t2, compute t0
    ITER(SLOT0, 192, 12, SLOT1);   // k=1: stage t3, compute t1
    ITER(SLOT1, 256, 12, SLOT2);   // k=2: stage t4, compute t2
    ITER(SLOT2, 320, 12, SLOT0);   // k=3: stage t5, compute t3
    ITER(SLOT0, 384, 12, SLOT1);   // k=4: stage t6, compute t4
    ITER(SLOT1, 448, 12, SLOT2);   // k=5: stage t7, compute t5
    ITER(SLOT2,  -1,  6, SLOT0);   // k=6: no stage, compute t6
    // k=7: nothing in flight needed beyond t7
    asm volatile("s_waitcnt vmcnt(0)" ::: "memory");
    BARRIER();
    COMPUTE(SLOT1);
    #undef ITER
    #undef COMPUTE
    #undef STAGE6

    // Epilogue: dis = -5*(f2 + c2 - 2*dot); exp; per-row sums; label capture.
    float* rs = rowsum + (size_t)(blockIdx.x & 7) * N_ROWS;  // per-XCD slice
    const float* f2s  = (const float*)(sm + SM_F2);
    const float* c2s  = (const float*)(sm + SM_C2);
    const int*   labs = (const int*)(sm + SM_LAB);
    #pragma unroll
    for (int m = 0; m < 4; ++m) {
        float s[4] = {0.f, 0.f, 0.f, 0.f};
        const int lr0 = wr * 64 + m * 16 + h4 * 4;
        #pragma unroll
        for (int n = 0; n < 4; ++n) {
            const int lcol = wc * 64 + n * 16 + l15;
            const int gcol = colBase + lcol;
            const float cc = c2s[lcol];
            #pragma unroll
            for (int j = 0; j < 4; ++j) {
                const int lr = lr0 + j;
                float dis = -5.0f * (f2s[lr] + cc - 2.0f * acc[m][n][j]);
                float e = __expf(dis);
                s[j] += e;
                if (labs[lr] == gcol) posdis[rowBase + lr] = dis;
            }
        }
        #pragma unroll
        for (int msk = 1; msk < 16; msk <<= 1) {
            #pragma unroll
            for (int j = 0; j < 4; ++j) s[j] += __shfl_xor(s[j], msk, 64);
        }
        if (l15 == 0) {
            #pragma unroll
            for (int j = 0; j < 4; ++j)
                atomicAdd(&rs[rowBase + lr0 + j], s[j]);
        }
    }
}

// Finalize stage 1: NPART blocks each reduce 256 rows -> f64 partial triple.
__global__ __launch_bounds__(256) void finalize_part_kernel(
    const float* __restrict__ posdis, const float* __restrict__ pose,
    const float* __restrict__ rowsum, const int* __restrict__ labels,
    const float* __restrict__ bias, double* __restrict__ partials)
{
    int t = threadIdx.x;
    int r = blockIdx.x * (N_ROWS / NPART) + t;
    float rsum = 0.f;
    #pragma unroll
    for (int x = 0; x < 8; ++x) rsum += rowsum[x * N_ROWS + r];
    float pd = posdis[r];                 // bf16-path label term (matches rowsum)
    float p  = pose[r] + bias[labels[r]]; // exact-path pos_metric
    float num = __expf(p);
    float den = rsum - __expf(pd) + num;
    double sl  = (double)(logf(den) - p);
    double sp  = (double)p;
    double sp2 = (double)p * (double)p;
    #pragma unroll
    for (int m = 1; m < 64; m <<= 1) {
        sl  += __shfl_xor(sl,  m, 64);
        sp  += __shfl_xor(sp,  m, 64);
        sp2 += __shfl_xor(sp2, m, 64);
    }
    __shared__ double sh[3][4];
    int w = t >> 6, lane = t & 63;
    if (lane == 0) { sh[0][w] = sl; sh[1][w] = sp; sh[2][w] = sp2; }
    __syncthreads();
    if (t == 0) {
        partials[blockIdx.x * 3 + 0] = sh[0][0] + sh[0][1] + sh[0][2] + sh[0][3];
        partials[blockIdx.x * 3 + 1] = sh[1][0] + sh[1][1] + sh[1][2] + sh[1][3];
        partials[blockIdx.x * 3 + 2] = sh[2][0] + sh[2][1] + sh[2][2] + sh[2][3];
    }
}

// Finalize stage 2: one wave combines NPART partials (deterministic order).
__global__ __launch_bounds__(64) void finalize_comb_kernel(
    const double* __restrict__ partials, float* __restrict__ out)
{
    int t = threadIdx.x;
    double sl = 0.0, sp = 0.0, sp2 = 0.0;
    if (t < NPART) {
        sl  = partials[t * 3 + 0];
        sp  = partials[t * 3 + 1];
        sp2 = partials[t * 3 + 2];
    }
    #pragma unroll
    for (int m = 1; m < 64; m <<= 1) {
        sl  += __shfl_xor(sl,  m, 64);
        sp  += __shfl_xor(sp,  m, 64);
        sp2 += __shfl_xor(sp2, m, 64);
    }
    if (t == 0) {
        const double N = (double)N_ROWS;
        double mean = sp / N;
        double var  = (sp2 - N * mean * mean) / (N - 1.0);
        out[0] = (float)(sl / N + var);
        out[1] = (float)var;
    }
}

extern "C" void kernel_launch(void* const* d_in, const int* in_sizes, int n_in,
                              void* d_out, int out_size, void* d_ws, size_t ws_size,
                              hipStream_t stream) {
    const float* features = (const float*)d_in[0];
    const int*   labels   = (const int*)d_in[1];
    const float* centers  = (const float*)d_in[2];
    const float* bias     = (const float*)d_in[3];
    float* out = (float*)d_out;
    char* ws = (char*)d_ws;

    // Workspace layout (16B aligned), ~19.3 MB total.
    u16*    fb     = (u16*)(ws);                 // 8192*512*2  = 8388608
    u16*    cb     = (u16*)(ws + 8388608);       // 10240*512*2 = 10485760
    float*  f2     = (float*)(ws + 18874368);    // 8192*4
    float*  c2     = (float*)(ws + 18907136);    // 10240*4
    float*  rowsum = (float*)(ws + 18948096);    // 8*8192*4 = 262144
    float*  posdis = (float*)(ws + 19210240);    // 8192*4
    float*  pose   = (float*)(ws + 19243008);    // 8192*4
    double* parts  = (double*)(ws + 19275776);   // 32*3*8 = 768

    hipMemsetAsync(rowsum, 0, 8 * N_ROWS * sizeof(float), stream);

    hipLaunchKernelGGL(prep_kernel, dim3(6656), dim3(256), 0, stream,
                       features, centers, labels, fb, cb, f2, c2, pose);

    hipFuncSetAttribute(reinterpret_cast<const void*>(gemm_kernel),
                        hipFuncAttributeMaxDynamicSharedMemorySize, SM_TOTAL);
    hipLaunchKernelGGL(gemm_kernel, dim3(C_PAD / BN, N_ROWS / BM), dim3(512), SM_TOTAL, stream,
                       fb, cb, f2, c2, labels, rowsum, posdis);

    hipLaunchKernelGGL(finalize_part_kernel, dim3(NPART), dim3(256), 0, stream,
                       posdis, pose, rowsum, labels, bias, parts);
    hipLaunchKernelGGL(finalize_comb_kernel, dim3(1), dim3(64), 0, stream,
                       parts, out);
}

// Round 14
// 163.001 us; speedup vs baseline: 1.2914x; 1.2914x over previous
//
#include <hip/hip_runtime.h>
#include <hip/hip_bf16.h>
#include <stdint.h>

typedef unsigned short u16;
typedef __bf16 v8bf __attribute__((ext_vector_type(8)));
typedef float  v4f  __attribute__((ext_vector_type(4)));

#define N_ROWS 8192
#define C_REAL 10000
#define C_PAD  10240   /* 80 * 128 */
#define D_DIM  512
#define BM 128
#define BN 128
#define BK2 32
#define NSTEP (D_DIM / BK2)   /* 16 */

/* LDS map (bytes): TWO 16KB step-slots (each: A 8KB = 128 rows x 64B
   swizzled, B 8KB @+8192), slot0 @0, slot1 @16384; tables f2s @32768,
   c2s @33280, labs @33792. Total 34304 — SAME footprint as round 11 =>
   4 blocks/CU, 16 waves (the strongest variable so far), but now double-
   buffered: per step {stage(s+1)->other slot; vmcnt(4) = counted wait on
   stage(s) issued a full step earlier; barrier; 8 ds_read + 16 MFMA;
   lgkmcnt(0); barrier}. Converts r11's exposed vmcnt(0) drain into a
   mostly-hidden counted wait (T4/m218) without losing occupancy. */
#define SM_SLOT  16384
#define SM_BOFF  8192
#define SM_F2    32768
#define SM_C2    33280
#define SM_LAB   33792
#define SM_TOTAL 34304
static_assert(4 * SM_TOTAL <= 160 * 1024, "want 4 blocks/CU");

#define NPART 32   /* finalize stage-1 blocks */

#define BARRIER() do { asm volatile("" ::: "memory"); \
                       __builtin_amdgcn_s_barrier();  \
                       asm volatile("" ::: "memory"); } while (0)
#define MFMA(d, a, b) d = __builtin_amdgcn_mfma_f32_16x16x32_bf16(a, b, d, 0, 0, 0)
#define GLL(gp, lp) __builtin_amdgcn_global_load_lds( \
    (const __attribute__((address_space(1))) void*)(gp), \
    (__attribute__((address_space(3))) void*)(lp), 16, 0, 0)

__device__ __forceinline__ unsigned pack2bf(float a, float b) {
    unsigned short ua = __builtin_bit_cast(unsigned short, (__bf16)a);
    unsigned short ub = __builtin_bit_cast(unsigned short, (__bf16)b);
    return (unsigned)ua | ((unsigned)ub << 16);
}

// L2-normalize one row (one wave): bf16 row out + f32 sum-of-squares of the
// normalized row. Padding rows: bf16 zeros, o2 = 1e30 (exp(-5e30) = 0).
__device__ __forceinline__ void norm_row(
    const float* __restrict__ x, u16* __restrict__ ob, float* __restrict__ o2,
    int row, int nreal, int lane)
{
    uint2* orow = (uint2*)(ob + (size_t)row * D_DIM);
    if (row >= nreal) {
        uint2 z; z.x = 0u; z.y = 0u;
        orow[lane] = z; orow[64 + lane] = z;
        if (lane == 0) o2[row] = 1e30f;
        return;
    }
    const float4* xr = (const float4*)(x + (size_t)row * D_DIM);
    float4 v0 = xr[lane];
    float4 v1 = xr[64 + lane];
    float s = v0.x*v0.x + v0.y*v0.y + v0.z*v0.z + v0.w*v0.w
            + v1.x*v1.x + v1.y*v1.y + v1.z*v1.z + v1.w*v1.w;
    #pragma unroll
    for (int m = 1; m < 64; m <<= 1) s += __shfl_xor(s, m, 64);
    float inv = 1.0f / fmaxf(sqrtf(s), 1e-12f);
    if (lane == 0) o2[row] = s * inv * inv;
    uint2 p0, p1;
    p0.x = pack2bf(v0.x * inv, v0.y * inv);
    p0.y = pack2bf(v0.z * inv, v0.w * inv);
    p1.x = pack2bf(v1.x * inv, v1.y * inv);
    p1.y = pack2bf(v1.z * inv, v1.w * inv);
    orow[lane]      = p0;
    orow[64 + lane] = p1;
}

// Exact (f32) positive-class distance for one row (one wave).
__device__ __forceinline__ void pos_row(
    const float* __restrict__ feat, const float* __restrict__ cent,
    const int* __restrict__ labels, float* __restrict__ pose,
    int row, int lane)
{
    int lab = labels[row];
    const float4* fr = (const float4*)(feat + (size_t)row * D_DIM);
    const float4* cr = (const float4*)(cent + (size_t)lab * D_DIM);
    float sf = 0.f, sc = 0.f, sd = 0.f;
    #pragma unroll
    for (int i = 0; i < 2; ++i) {
        float4 a = fr[i * 64 + lane];
        float4 b = cr[i * 64 + lane];
        sf += a.x*a.x + a.y*a.y + a.z*a.z + a.w*a.w;
        sc += b.x*b.x + b.y*b.y + b.z*b.z + b.w*b.w;
        sd += a.x*b.x + a.y*b.y + a.z*b.z + a.w*b.w;
    }
    #pragma unroll
    for (int m = 1; m < 64; m <<= 1) {
        sf += __shfl_xor(sf, m, 64);
        sc += __shfl_xor(sc, m, 64);
        sd += __shfl_xor(sd, m, 64);
    }
    if (lane == 0) {
        float invf = 1.f / fmaxf(sqrtf(sf), 1e-12f);
        float invc = 1.f / fmaxf(sqrtf(sc), 1e-12f);
        pose[row] = -5.0f * (sf * invf * invf + sc * invc * invc
                             - 2.0f * sd * invf * invc);
    }
}

// Fused prep: one launch covers norm(features), norm(centers+pad), pos_exact.
__global__ __launch_bounds__(256) void prep_kernel(
    const float* __restrict__ features, const float* __restrict__ centers,
    const int* __restrict__ labels,
    u16* __restrict__ fb, u16* __restrict__ cb,
    float* __restrict__ f2, float* __restrict__ c2, float* __restrict__ pose)
{
    int b = blockIdx.x;
    int sub = threadIdx.x >> 6;
    int lane = threadIdx.x & 63;
    if (b < 2048) {
        norm_row(features, fb, f2, b * 4 + sub, N_ROWS, lane);
    } else if (b < 4608) {
        norm_row(centers, cb, c2, (b - 2048) * 4 + sub, C_REAL, lane);
    } else {
        pos_row(features, centers, labels, pose, (b - 4608) * 4 + sub, lane);
    }
}

// 128x128x(BK=32) 4-wave MFMA GEMM, double-buffered 16KB step-slots,
// 4 blocks/CU (16 waves). Swizzle for 64B rows: physical chunk =
// logical ^ ((row>>1)&3); staging-thread invariance holds (+64 rows
// preserves (row>>1)&3) and the b128 fragment read maps exactly 8 lanes
// to each 4-bank group (balanced = conflict-free minimum for b128).
// Fragment K-layout (h4 -> elems 8*h4..8*h4+7) unchanged from r9/r11.
// Grid (80,64): 80%8==0 => XCD = x%8 => per-XCD B-slice 1.3MB + window
// A ~1MB < 4MB L2 (r11 measured FETCH 38MB). Fused exp epilogue.
__global__ __launch_bounds__(256, 4) void gemm_kernel(
    const u16* __restrict__ A, const u16* __restrict__ B,
    const float* __restrict__ f2, const float* __restrict__ c2,
    const int* __restrict__ labels,
    float* __restrict__ rowsum, float* __restrict__ posdis)
{
    extern __shared__ char sm[];
    const int rowBase = blockIdx.y * BM;
    const int colBase = blockIdx.x * BN;
    const int tid  = threadIdx.x;
    const int lane = tid & 63;
    const int w    = tid >> 6;      // 0..3
    const int wr   = w >> 1;        // 0..1 : 64-row group
    const int wc   = w & 1;         // 0..1 : 64-col group
    const int l15  = lane & 15;
    const int h4   = lane >> 4;

    // ---- staging geometry: per matrix sub-tile 128 rows x 4 chunks(16B);
    // thread covers chunks c = tid (r = tid>>2) and c = tid+256 (r + 64);
    // pc = tid&3, lc = pc ^ ((r>>1)&3), invariant under +64.
    const int r0  = tid >> 2;                       // 0..63
    const int lc0 = (tid & 3) ^ ((tid >> 3) & 3);   // (r0>>1)&3 = (tid>>3)&3
    const size_t gOff = (size_t)r0 * D_DIM + lc0 * 8;   // elements
    const u16* aP = A + (size_t)rowBase * D_DIM + gOff; // +32768 elems for +64 rows
    const u16* bP = B + (size_t)colBase * D_DIM + gOff;
    const int d0 = tid * 16;                            // LDS bytes; +4096 for i=1

    // Stage step s (KOFS = s*32 elements) into slot at byte base SL.
    #define STAGE4(SL, KOFS) do { \
        GLL(aP + (KOFS),         sm + (SL) + d0);                  \
        GLL(aP + (KOFS) + 32768, sm + (SL) + 4096 + d0);           \
        GLL(bP + (KOFS),         sm + (SL) + SM_BOFF + d0);        \
        GLL(bP + (KOFS) + 32768, sm + (SL) + SM_BOFF + 4096 + d0); \
    } while (0)

    // ---- fragment read bases; row = g*64 + m*16 + l15 => (row>>1)&3 =
    // (l15>>1)&3 (g*32, m*8 vanish mod 4) => swizzled byte col =
    // (h4 ^ ((l15>>1)&3)) * 16, independent of m.
    const int sw  = (h4 ^ ((l15 >> 1) & 3)) << 4;
    const int aO  = wr * 4096 + l15 * 64 + sw;
    const int bO  = SM_BOFF + wc * 4096 + l15 * 64 + sw;

    // ---- prologue: epilogue tables + step 0 into slot0; full drain once ----
    if (tid < 128) {
        ((float*)(sm + SM_F2))[tid] = f2[rowBase + tid];
        ((int*)(sm + SM_LAB))[tid]  = labels[rowBase + tid];
    } else {
        ((float*)(sm + SM_C2))[tid - 128] = c2[colBase + (tid - 128)];
    }
    STAGE4(0, 0);
    __syncthreads();

    v4f acc[4][4];
    #pragma unroll
    for (int m = 0; m < 4; ++m)
        #pragma unroll
        for (int n = 0; n < 4; ++n) acc[m][n] = (v4f){0.f, 0.f, 0.f, 0.f};

    // Steady state: stage(s+1) -> counted vmcnt(4) [stage(s) landed, the 4
    // just-issued stay in flight] -> barrier -> compute(s) -> lgkmcnt(0) ->
    // barrier [slot (s+1)&1 ... stage at step s+1 overwrites slot s&1 only
    // after this barrier, when all reads of it have retired].
    #pragma unroll
    for (int k = 0; k < NSTEP; ++k) {
        const int slc = (k & 1) * SM_SLOT;          // compile-time per iter
        if (k + 1 < NSTEP) {
            const int sls = ((k + 1) & 1) * SM_SLOT;
            STAGE4(sls, (k + 1) * BK2);
            asm volatile("s_waitcnt vmcnt(4)" ::: "memory");
        } else {
            asm volatile("s_waitcnt vmcnt(0)" ::: "memory");
        }
        BARRIER();

        v8bf a[4], b[4];
        #pragma unroll
        for (int m = 0; m < 4; ++m) a[m] = *(const v8bf*)(sm + slc + aO + m * 1024);
        #pragma unroll
        for (int n = 0; n < 4; ++n) b[n] = *(const v8bf*)(sm + slc + bO + n * 1024);
        __builtin_amdgcn_s_setprio(1);
        #pragma unroll
        for (int m = 0; m < 4; ++m)
            #pragma unroll
            for (int n = 0; n < 4; ++n)
                MFMA(acc[m][n], a[m], b[n]);
        __builtin_amdgcn_s_setprio(0);

        if (k + 1 < NSTEP) {
            asm volatile("s_waitcnt lgkmcnt(0)" ::: "memory");
            BARRIER();
        }
    }
    #undef STAGE4

    // Epilogue: dis = -5*(f2 + c2 - 2*dot); exp; per-row sums; label capture.
    float* rs = rowsum + (size_t)(blockIdx.x & 7) * N_ROWS;  // per-XCD slice
    const float* f2s  = (const float*)(sm + SM_F2);
    const float* c2s  = (const float*)(sm + SM_C2);
    const int*   labs = (const int*)(sm + SM_LAB);
    #pragma unroll
    for (int m = 0; m < 4; ++m) {
        float s[4] = {0.f, 0.f, 0.f, 0.f};
        const int lr0 = wr * 64 + m * 16 + h4 * 4;
        #pragma unroll
        for (int n = 0; n < 4; ++n) {
            const int lcol = wc * 64 + n * 16 + l15;
            const int gcol = colBase + lcol;
            const float cc = c2s[lcol];
            #pragma unroll
            for (int j = 0; j < 4; ++j) {
                const int lr = lr0 + j;
                float dis = -5.0f * (f2s[lr] + cc - 2.0f * acc[m][n][j]);
                float e = __expf(dis);
                s[j] += e;
                if (labs[lr] == gcol) posdis[rowBase + lr] = dis;
            }
        }
        #pragma unroll
        for (int msk = 1; msk < 16; msk <<= 1) {
            #pragma unroll
            for (int j = 0; j < 4; ++j) s[j] += __shfl_xor(s[j], msk, 64);
        }
        if (l15 == 0) {
            #pragma unroll
            for (int j = 0; j < 4; ++j)
                atomicAdd(&rs[rowBase + lr0 + j], s[j]);
        }
    }
}

// Finalize stage 1: NPART blocks each reduce 256 rows -> f64 partial triple.
__global__ __launch_bounds__(256) void finalize_part_kernel(
    const float* __restrict__ posdis, const float* __restrict__ pose,
    const float* __restrict__ rowsum, const int* __restrict__ labels,
    const float* __restrict__ bias, double* __restrict__ partials)
{
    int t = threadIdx.x;
    int r = blockIdx.x * (N_ROWS / NPART) + t;
    float rsum = 0.f;
    #pragma unroll
    for (int x = 0; x < 8; ++x) rsum += rowsum[x * N_ROWS + r];
    float pd = posdis[r];                 // bf16-path label term (matches rowsum)
    float p  = pose[r] + bias[labels[r]]; // exact-path pos_metric
    float num = __expf(p);
    float den = rsum - __expf(pd) + num;
    double sl  = (double)(logf(den) - p);
    double sp  = (double)p;
    double sp2 = (double)p * (double)p;
    #pragma unroll
    for (int m = 1; m < 64; m <<= 1) {
        sl  += __shfl_xor(sl,  m, 64);
        sp  += __shfl_xor(sp,  m, 64);
        sp2 += __shfl_xor(sp2, m, 64);
    }
    __shared__ double sh[3][4];
    int w = t >> 6, lane = t & 63;
    if (lane == 0) { sh[0][w] = sl; sh[1][w] = sp; sh[2][w] = sp2; }
    __syncthreads();
    if (t == 0) {
        partials[blockIdx.x * 3 + 0] = sh[0][0] + sh[0][1] + sh[0][2] + sh[0][3];
        partials[blockIdx.x * 3 + 1] = sh[1][0] + sh[1][1] + sh[1][2] + sh[1][3];
        partials[blockIdx.x * 3 + 2] = sh[2][0] + sh[2][1] + sh[2][2] + sh[2][3];
    }
}

// Finalize stage 2: one wave combines NPART partials (deterministic order).
__global__ __launch_bounds__(64) void finalize_comb_kernel(
    const double* __restrict__ partials, float* __restrict__ out)
{
    int t = threadIdx.x;
    double sl = 0.0, sp = 0.0, sp2 = 0.0;
    if (t < NPART) {
        sl  = partials[t * 3 + 0];
        sp  = partials[t * 3 + 1];
        sp2 = partials[t * 3 + 2];
    }
    #pragma unroll
    for (int m = 1; m < 64; m <<= 1) {
        sl  += __shfl_xor(sl,  m, 64);
        sp  += __shfl_xor(sp,  m, 64);
        sp2 += __shfl_xor(sp2, m, 64);
    }
    if (t == 0) {
        const double N = (double)N_ROWS;
        double mean = sp / N;
        double var  = (sp2 - N * mean * mean) / (N - 1.0);
        out[0] = (float)(sl / N + var);
        out[1] = (float)var;
    }
}

extern "C" void kernel_launch(void* const* d_in, const int* in_sizes, int n_in,
                              void* d_out, int out_size, void* d_ws, size_t ws_size,
                              hipStream_t stream) {
    const float* features = (const float*)d_in[0];
    const int*   labels   = (const int*)d_in[1];
    const float* centers  = (const float*)d_in[2];
    const float* bias     = (const float*)d_in[3];
    float* out = (float*)d_out;
    char* ws = (char*)d_ws;

    // Workspace layout (16B aligned), ~19.3 MB total.
    u16*    fb     = (u16*)(ws);                 // 8192*512*2  = 8388608
    u16*    cb     = (u16*)(ws + 8388608);       // 10240*512*2 = 10485760
    float*  f2     = (float*)(ws + 18874368);    // 8192*4
    float*  c2     = (float*)(ws + 18907136);    // 10240*4
    float*  rowsum = (float*)(ws + 18948096);    // 8*8192*4 = 262144
    float*  posdis = (float*)(ws + 19210240);    // 8192*4
    float*  pose   = (float*)(ws + 19243008);    // 8192*4
    double* parts  = (double*)(ws + 19275776);   // 32*3*8 = 768

    hipMemsetAsync(rowsum, 0, 8 * N_ROWS * sizeof(float), stream);

    hipLaunchKernelGGL(prep_kernel, dim3(6656), dim3(256), 0, stream,
                       features, centers, labels, fb, cb, f2, c2, pose);

    hipFuncSetAttribute(reinterpret_cast<const void*>(gemm_kernel),
                        hipFuncAttributeMaxDynamicSharedMemorySize, SM_TOTAL);
    hipLaunchKernelGGL(gemm_kernel, dim3(C_PAD / BN, N_ROWS / BM), dim3(256), SM_TOTAL, stream,
                       fb, cb, f2, c2, labels, rowsum, posdis);

    hipLaunchKernelGGL(finalize_part_kernel, dim3(NPART), dim3(256), 0, stream,
                       posdis, pose, rowsum, labels, bias, parts);
    hipLaunchKernelGGL(finalize_comb_kernel, dim3(1), dim3(64), 0, stream,
                       parts, out);
}